// Round 2
// baseline (127.126 us; speedup 1.0000x reference)
//
#include <hip/hip_runtime.h>
#include <math.h>

#define LATN 721
#define LONN 1440
#define NLEV 13
#define NBATCH 2
#define SLICE (LATN * LONN)              // 1,038,240
#define BATSTRIDE (NLEV * SLICE)

// fused-tile geometry
#define TI 8
#define TJ 32
#define HR (TI + 2)                      // 10 halo rows
#define HC (TJ + 2)                      // 34 halo cols
#define HRHC (HR * HC)                   // 340
#define NRT 91                           // ceil(721/8)
#define NCT 45                           // 1440/32
#define NWG (NRT * NCT)                  // 4095

// ---- ws float layout ----
#define NBANK      128
#define BANKSTRIDE 64
#define WS_ACC     0                     // [NBANK*BANKSTRIDE]
#define ACC_SUM    0        // [26] per (b,l) sums
#define ACC_SSQ    26       // [2]  per-batch total sum-of-squares (collapsed over l)
#define ACC_GRAD   28
#define ACC_MASS   29
#define N_ACC      30
#define WS_INVDX   (NBANK * BANKSTRIDE)          // [721]
#define WS_FCOR    (WS_INVDX + LATN)             // [721]
#define WS_W       (WS_FCOR + LATN)             // [13]
#define WS_INVDP   (WS_W + NLEV)
#define WS_INV2DP  (WS_INVDP + 1)

constexpr float INV_R     = (float)(1.0 / 6371000.0);
constexpr float INV_DLAT  = (float)(720.0 / M_PI);
constexpr float INV_2DLAT = (float)(360.0 / M_PI);
constexpr float INV_DLON  = (float)(1440.0 / (2.0 * M_PI));
constexpr float INV_2DLON = (float)(720.0 / (2.0 * M_PI));
constexpr float QG_COEF   = 1e-4f;   // F0^2 / N^2

// ---------------- setup: row tables, weights, zero accumulators ----------------
__global__ void pl_setup_kernel(const float* __restrict__ plev, float* __restrict__ ws) {
    const int t = threadIdx.x;
    if (t < LATN) {
        double lat;
        if (t == 0)            lat = (double)(-(float)(M_PI / 2.0));
        else if (t == LATN-1)  lat = (double)( (float)(M_PI / 2.0));
        else                   lat = (double)((float)(-M_PI / 2.0 + (double)t * (M_PI / 720.0)));
        double c = cos(lat);
        if (c < 1e-8) c = 1e-8;                      // matches jnp.clip(cos, 1e-8)
        ws[WS_INVDX + t] = (float)(1.0 / (6371000.0 * c));
        ws[WS_FCOR  + t] = (float)(2.0 * 7.292e-05 * sin(lat));
    }
    if (t < NLEV) {
        float p[NLEV];
        #pragma unroll
        for (int l = 0; l < NLEV; ++l) p[l] = plev[l] * 100.0f;
        float dpl[NLEV-1];
        #pragma unroll
        for (int l = 0; l < NLEV-1; ++l) dpl[l] = p[l+1] - p[l];
        float raw;
        if (t == 0)            raw = dpl[0] * 0.5f;
        else if (t == NLEV-1)  raw = dpl[NLEV-2] * 0.5f;
        else                   raw = (dpl[t-1] + dpl[t]) * 0.5f;
        float s = dpl[0] * 0.5f + dpl[NLEV-2] * 0.5f;
        #pragma unroll
        for (int l = 1; l < NLEV-1; ++l) s += (dpl[l-1] + dpl[l]) * 0.5f;
        if (s < 1e-8f) s = 1e-8f;
        ws[WS_W + t] = raw / s;
    }
    if (t == 0) {
        float sd = 0.f;
        for (int l = 0; l < NLEV-1; ++l) sd += plev[l+1] - plev[l];
        float dp = sd / (float)(NLEV-1) * 100.0f;    // mean(diff)*100 (hPa->Pa)
        ws[WS_INVDP]  = 1.0f / dp;
        ws[WS_INV2DP] = 1.0f / (2.0f * dp);
    }
    for (int z = t; z < NBANK * BANKSTRIDE; z += 1024) ws[WS_ACC + z] = 0.0f;
}

// ---------------- helpers ----------------
__device__ __forceinline__ int swz_nwg(int orig, int nwg) {
    // bijective XCD-chunk swizzle (m204)
    const int q = nwg >> 3, r = nwg & 7;
    const int x = orig & 7, k = orig >> 3;
    return (x < r ? x * (q + 1) : r * (q + 1) + (x - r) * q) + k;
}

// ---------------- fused kernel: qg + weighted-column U,V in LDS, one pass ----------------
// __launch_bounds__(256, 8): 8 WG/CU -> 32 waves/CU; forces VGPR <= 64 (m69 step)
__launch_bounds__(256, 8)
__global__ void pl_fused_kernel(const float* __restrict__ u, const float* __restrict__ v,
                                float* __restrict__ ws)
{
    __shared__ float qg[NLEV * HRHC];        // 17,680 B
    __shared__ float uvred[2 * HRHC];        // Ucol/Vcol; re-used as red[16][16] after barrier
    float* Ucol = uvred;
    float* Vcol = uvred + HRHC;
    // total LDS = 20,400 B -> 8 WG/CU at 160 KiB

    const int b  = blockIdx.y;
    const int wg = swz_nwg(blockIdx.x, NWG);
    const int rt = wg / NCT, ct = wg - rt * NCT;
    const int i0 = rt * TI, j0 = ct * TJ;

    const float* ub = u + (size_t)b * BATSTRIDE;
    const float* vb = v + (size_t)b * BATSTRIDE;
    // force uniform scalars into SGPRs (frees ~15 VGPRs)
    const float idp  = __builtin_amdgcn_readfirstlane(ws[WS_INVDP]);
    const float i2dp = __builtin_amdgcn_readfirstlane(ws[WS_INV2DP]);
    float wlev[NLEV];
    #pragma unroll
    for (int l = 0; l < NLEV; ++l) wlev[l] = __builtin_amdgcn_readfirstlane(ws[WS_W + l]);

    // ---- phase 1: qg + U,V for halo region into LDS (the ONLY global loads) ----
    for (int hidx = threadIdx.x; hidx < HRHC; hidx += 256) {
        const int hr = hidx / HC, hc = hidx - hr * HC;
        int r = i0 - 1 + hr; r = max(0, min(r, LATN - 1));
        int c = j0 - 1 + hc; c = max(0, min(c, LONN - 1));
        const int ro  = r * LONN;
        const int rpo = min(r + 1, LATN - 1) * LONN;
        const int rmo = max(r - 1, 0) * LONN;
        const int cp  = min(c + 1, LONN - 1);
        const int cm  = max(c - 1, 0);
        const float sc = ((c == 0 || c == LONN - 1) ? INV_DLON : INV_2DLON) * ws[WS_INVDX + r];
        const float sr = ((r == 0 || r == LATN - 1) ? INV_DLAT : INV_2DLAT) * INV_R;
        const float fc = ws[WS_FCOR + r];

        float vo[NLEV];
        float wu = 0.f, wv = 0.f;
        #pragma unroll
        for (int l = 0; l < NLEV; ++l) {
            const size_t o = (size_t)l * SLICE;
            vo[l] = (vb[o + ro + cp] - vb[o + ro + cm]) * sc
                  - (ub[o + rpo + c] - ub[o + rmo + c]) * sr;
            wu = fmaf(wlev[l], ub[o + ro + c], wu);
            wv = fmaf(wlev[l], vb[o + ro + c], wv);
        }
        Ucol[hidx] = wu;
        Vcol[hidx] = wv;

        // rolling 3-reg window for the vertical stencil (live set ~5 vs 26 regs;
        // bitwise-identical math to the vp1[] array form)
        float vp1m = (vo[1] - vo[0]) * idp;          // vp1[0]
        float vp1c = (vo[2] - vo[0]) * i2dp;         // vp1[1]
        qg[0 * HRHC + hidx] = vo[0] + fc + QG_COEF * ((vp1c - vp1m) * idp);
        #pragma unroll
        for (int l = 1; l < NLEV - 1; ++l) {
            const float vp1n = (l == NLEV - 2) ? (vo[NLEV-1] - vo[NLEV-2]) * idp
                                               : (vo[l+2] - vo[l]) * i2dp;   // vp1[l+1]
            qg[l * HRHC + hidx] = vo[l] + fc + QG_COEF * ((vp1n - vp1m) * i2dp);
            vp1m = vp1c; vp1c = vp1n;
        }
        qg[(NLEV-1) * HRHC + hidx] = vo[NLEV-1] + fc + QG_COEF * ((vp1c - vp1m) * idp);
    }
    __syncthreads();

    // ---- phase 2: pure-LDS stencils, zero global traffic ----
    const int oi = threadIdx.x >> 5, oj = threadIdx.x & 31;
    const int i = i0 + oi, j = j0 + oj;
    const float mval = (i < LATN) ? 1.f : 0.f;
    const int ic = min(i, LATN - 1);
    const int hb = (oi + 1) * HC + (oj + 1);
    const float siR = ((ic == 0 || ic == LATN - 1) ? INV_DLAT : INV_2DLAT) * INV_R;
    const float sjx = ((j == 0 || j == LONN - 1) ? INV_DLON : INV_2DLON) * ws[WS_INVDX + ic];

    float vals[16];
    float ssqt = 0.f, grad = 0.f;
    #pragma unroll
    for (int l = 0; l < NLEV; ++l) {
        const int base = l * HRHC + hb;
        const float qc = qg[base];
        const float gl = (qg[base + HC] - qg[base - HC]) * siR;
        const float gn = (qg[base + 1]  - qg[base - 1])  * sjx;
        vals[l] = qc;
        ssqt += qc * qc;
        grad += gl * gl + gn * gn;
    }
    const float du = (Ucol[hb + 1]  - Ucol[hb - 1])  * sjx;
    const float dv = (Vcol[hb + HC] - Vcol[hb - HC]) * siR;
    const float cd = du + dv;
    vals[13] = ssqt;
    vals[14] = grad;
    vals[15] = cd * cd;

    // ---- reduction: 4-step 16-lane-group butterfly + LDS transpose (16 values) ----
    #pragma unroll
    for (int k = 0; k < 16; ++k) {
        float x = vals[k] * mval;
        x += __shfl_xor(x, 8, 64);
        x += __shfl_xor(x, 4, 64);
        x += __shfl_xor(x, 2, 64);
        x += __shfl_xor(x, 1, 64);
        vals[k] = x;   // every lane in an aligned 16-group now holds all 16 group sums
    }
    const int g = threadIdx.x >> 4, k16 = threadIdx.x & 15;
    float myv = vals[0];
    #pragma unroll
    for (int k = 1; k < 16; ++k) if (k16 == k) myv = vals[k];   // static-index select (no scratch)

    __syncthreads();                         // all Ucol/Vcol reads done -> safe to re-use as red
    float (*red)[16] = (float (*)[16])uvred;
    red[g][k16] = myv;
    __syncthreads();

    if (threadIdx.x < 16) {
        const int k = threadIdx.x;
        float s = 0.f;
        #pragma unroll
        for (int g2 = 0; g2 < 16; ++g2) s += red[g2][k];
        int target;
        if (k < 13)       target = ACC_SUM + b * 13 + k;
        else if (k == 13) target = ACC_SSQ + b;
        else if (k == 14) target = ACC_GRAD;
        else              target = ACC_MASS;
        const int bank = (b * NWG + blockIdx.x) & (NBANK - 1);
        atomicAdd(&ws[WS_ACC + bank * BANKSTRIDE + target], s);
    }
}

// ---------------- finalize: sum banks, apply formulas ----------------
__global__ void pl_finalize_kernel(const float* __restrict__ ws, float* __restrict__ out) {
    __shared__ float tot[N_ACC];
    const int t = threadIdx.x;
    if (t < N_ACC) {
        float s = 0.f;
        for (int bk = 0; bk < NBANK; ++bk) s += ws[WS_ACC + bk * BANKSTRIDE + t];
        tot[t] = s;
    }
    __syncthreads();
    if (t == 0) {
        const float N = (float)SLICE;
        float s2 = 0.f;
        for (int s = 0; s < 2 * NLEV; ++s) s2 += tot[ACC_SUM + s] * tot[ACC_SUM + s];
        const float ssq = tot[ACC_SSQ + 0] + tot[ACC_SSQ + 1];
        // sum over (b,l) of (ssq_bl - sum_bl^2/N)/(N-1), then /26 — ssq collapsed by linearity
        float vmean = (ssq - s2 / N) / (N - 1.0f) * (1.0f / (2.0f * NLEV));
        float gmean = tot[ACC_GRAD] / (float)(NBATCH * NLEV * SLICE);
        float mmean = tot[ACC_MASS] / (float)(NBATCH * SLICE);
        out[0] = vmean + 0.1f * gmean + mmean;          // spectra_loss statically 0
    }
}

extern "C" void kernel_launch(void* const* d_in, const int* in_sizes, int n_in,
                              void* d_out, int out_size, void* d_ws, size_t ws_size,
                              hipStream_t stream) {
    const float* u    = (const float*)d_in[0];
    const float* v    = (const float*)d_in[1];
    const float* plev = (const float*)d_in[2];
    float* ws  = (float*)d_ws;
    float* out = (float*)d_out;

    hipLaunchKernelGGL(pl_setup_kernel, dim3(1), dim3(1024), 0, stream, plev, ws);
    hipLaunchKernelGGL(pl_fused_kernel, dim3(NWG, NBATCH), dim3(256), 0, stream, u, v, ws);
    hipLaunchKernelGGL(pl_finalize_kernel, dim3(1), dim3(64), 0, stream, ws, out);
}

// Round 3
// 92.416 us; speedup vs baseline: 1.3756x; 1.3756x over previous
//
#include <hip/hip_runtime.h>
#include <math.h>

#define LATN 721
#define LONN 1440
#define NLEV 13
#define NBATCH 2
#define SLICE (LATN * LONN)              // 1,038,240
#define BATSTRIDE (NLEV * SLICE)

// fused-tile geometry (TI=12: halo ratio 476/384=1.24, phase1 iters 256+220)
#define TI 12
#define TJ 32
#define HR (TI + 2)                      // 14 halo rows
#define HC (TJ + 2)                      // 34 halo cols
#define HRHC (HR * HC)                   // 476
#define NPTS (TI * TJ)                   // 384 interior points
#define NRT 61                           // ceil(721/12)
#define NCT 45                           // 1440/32
#define NWG (NRT * NCT)                  // 2745

// ---- ws float layout ----
#define NBANK      128
#define BANKSTRIDE 64
#define WS_ACC     0                     // [NBANK*BANKSTRIDE]
#define ACC_SUM    0        // [26] per (b,l) sums
#define ACC_SSQ    26       // [2]  per-batch total sum-of-squares (collapsed over l)
#define ACC_GRAD   28
#define ACC_MASS   29
#define N_ACC      30
#define WS_INVDX   (NBANK * BANKSTRIDE)          // [721]
#define WS_FCOR    (WS_INVDX + LATN)             // [721]
#define WS_W       (WS_FCOR + LATN)              // [13]
#define WS_INVDP   (WS_W + NLEV)
#define WS_INV2DP  (WS_INVDP + 1)

constexpr float INV_R     = (float)(1.0 / 6371000.0);
constexpr float INV_DLAT  = (float)(720.0 / M_PI);
constexpr float INV_2DLAT = (float)(360.0 / M_PI);
constexpr float INV_DLON  = (float)(1440.0 / (2.0 * M_PI));
constexpr float INV_2DLON = (float)(720.0 / (2.0 * M_PI));
constexpr float QG_COEF   = 1e-4f;   // F0^2 / N^2

// ---------------- setup: row tables, weights, zero accumulators ----------------
__global__ void pl_setup_kernel(const float* __restrict__ plev, float* __restrict__ ws) {
    const int t = threadIdx.x;
    if (t < LATN) {
        double lat;
        if (t == 0)            lat = (double)(-(float)(M_PI / 2.0));
        else if (t == LATN-1)  lat = (double)( (float)(M_PI / 2.0));
        else                   lat = (double)((float)(-M_PI / 2.0 + (double)t * (M_PI / 720.0)));
        double c = cos(lat);
        if (c < 1e-8) c = 1e-8;                      // matches jnp.clip(cos, 1e-8)
        ws[WS_INVDX + t] = (float)(1.0 / (6371000.0 * c));
        ws[WS_FCOR  + t] = (float)(2.0 * 7.292e-05 * sin(lat));
    }
    if (t < NLEV) {
        float p[NLEV];
        #pragma unroll
        for (int l = 0; l < NLEV; ++l) p[l] = plev[l] * 100.0f;
        float dpl[NLEV-1];
        #pragma unroll
        for (int l = 0; l < NLEV-1; ++l) dpl[l] = p[l+1] - p[l];
        float raw;
        if (t == 0)            raw = dpl[0] * 0.5f;
        else if (t == NLEV-1)  raw = dpl[NLEV-2] * 0.5f;
        else                   raw = (dpl[t-1] + dpl[t]) * 0.5f;
        float s = dpl[0] * 0.5f + dpl[NLEV-2] * 0.5f;
        #pragma unroll
        for (int l = 1; l < NLEV-1; ++l) s += (dpl[l-1] + dpl[l]) * 0.5f;
        if (s < 1e-8f) s = 1e-8f;
        ws[WS_W + t] = raw / s;
    }
    if (t == 0) {
        float sd = 0.f;
        for (int l = 0; l < NLEV-1; ++l) sd += plev[l+1] - plev[l];
        float dp = sd / (float)(NLEV-1) * 100.0f;    // mean(diff)*100 (hPa->Pa)
        ws[WS_INVDP]  = 1.0f / dp;
        ws[WS_INV2DP] = 1.0f / (2.0f * dp);
    }
    for (int z = t; z < NBANK * BANKSTRIDE; z += 1024) ws[WS_ACC + z] = 0.0f;
}

// ---------------- helpers ----------------
__device__ __forceinline__ int swz_nwg(int orig, int nwg) {
    // bijective XCD-chunk swizzle (m204)
    const int q = nwg >> 3, r = nwg & 7;
    const int x = orig & 7, k = orig >> 3;
    return (x < r ? x * (q + 1) : r * (q + 1) + (x - r) * q) + k;
}

// ---------------- fused kernel: qg + weighted-column U,V in LDS, one pass ----------------
// (256,4): VGPR cap 128 — keep R1's fat-ILP allocation (R2 showed strangling VGPRs loses)
__launch_bounds__(256, 4)
__global__ void pl_fused_kernel(const float* __restrict__ u, const float* __restrict__ v,
                                float* __restrict__ ws)
{
    __shared__ float qg[NLEV * HRHC];        // 24,752 B
    __shared__ float uvred[2 * HRHC];        // Ucol/Vcol; re-used as red[16][16] after barrier
    float* Ucol = uvred;
    float* Vcol = uvred + HRHC;
    // total LDS = 28,560 B -> 5 WG/CU at 160 KiB

    const int b  = blockIdx.y;
    const int wg = swz_nwg(blockIdx.x, NWG);
    const int rt = wg / NCT, ct = wg - rt * NCT;
    const int i0 = rt * TI, j0 = ct * TJ;

    const float* ub = u + (size_t)b * BATSTRIDE;
    const float* vb = v + (size_t)b * BATSTRIDE;
    const float idp = ws[WS_INVDP], i2dp = ws[WS_INV2DP];

    // ---- phase 1: qg + U,V for halo region into LDS (the ONLY global loads) ----
    for (int hidx = threadIdx.x; hidx < HRHC; hidx += 256) {
        const int hr = hidx / HC, hc = hidx - hr * HC;
        int r = i0 - 1 + hr; r = max(0, min(r, LATN - 1));
        int c = j0 - 1 + hc; c = max(0, min(c, LONN - 1));
        // 5 per-point VGPR offsets; per-level advance is a uniform (SGPR) pointer bump
        const int occ = r * LONN + c;
        const int ocp = r * LONN + min(c + 1, LONN - 1);
        const int ocm = r * LONN + max(c - 1, 0);
        const int opc = min(r + 1, LATN - 1) * LONN + c;
        const int omc = max(r - 1, 0) * LONN + c;
        const float sc = ((c == 0 || c == LONN - 1) ? INV_DLON : INV_2DLON) * ws[WS_INVDX + r];
        const float sr = ((r == 0 || r == LATN - 1) ? INV_DLAT : INV_2DLAT) * INV_R;
        const float fc = ws[WS_FCOR + r];

        float vo[NLEV];
        float wu = 0.f, wv = 0.f;
        const float* up = ub;
        const float* vp = vb;
        #pragma unroll
        for (int l = 0; l < NLEV; ++l) {
            const float wl = ws[WS_W + l];               // uniform scalar load
            vo[l] = (vp[ocp] - vp[ocm]) * sc - (up[opc] - up[omc]) * sr;
            wu = fmaf(wl, up[occ], wu);
            wv = fmaf(wl, vp[occ], wv);
            up += SLICE; vp += SLICE;                    // SALU pointer bump
        }
        Ucol[hidx] = wu;
        Vcol[hidx] = wv;

        // rolling 3-reg window for the vertical stencil (bitwise-identical to vp1[] form)
        float vp1m = (vo[1] - vo[0]) * idp;              // vp1[0]
        float vp1c = (vo[2] - vo[0]) * i2dp;             // vp1[1]
        qg[0 * HRHC + hidx] = vo[0] + fc + QG_COEF * ((vp1c - vp1m) * idp);
        #pragma unroll
        for (int l = 1; l < NLEV - 1; ++l) {
            const float vp1n = (l == NLEV - 2) ? (vo[NLEV-1] - vo[NLEV-2]) * idp
                                               : (vo[l+2] - vo[l]) * i2dp;   // vp1[l+1]
            qg[l * HRHC + hidx] = vo[l] + fc + QG_COEF * ((vp1n - vp1m) * i2dp);
            vp1m = vp1c; vp1c = vp1n;
        }
        qg[(NLEV-1) * HRHC + hidx] = vo[NLEV-1] + fc + QG_COEF * ((vp1c - vp1m) * idp);
    }
    __syncthreads();

    // ---- phase 2: pure-LDS stencils over the 384 interior points, zero global traffic ----
    float vals[16];
    #pragma unroll
    for (int k = 0; k < 16; ++k) vals[k] = 0.f;

    for (int p = threadIdx.x; p < NPTS; p += 256) {
        const int oi = p >> 5, oj = p & 31;
        const int i = i0 + oi, j = j0 + oj;
        const float mval = (i < LATN) ? 1.f : 0.f;
        const int ic = min(i, LATN - 1);
        const int hb = (oi + 1) * HC + (oj + 1);
        const float siR = ((ic == 0 || ic == LATN - 1) ? INV_DLAT : INV_2DLAT) * INV_R;
        const float sjx = ((j == 0 || j == LONN - 1) ? INV_DLON : INV_2DLON) * ws[WS_INVDX + ic];

        float ssqt = 0.f, grad = 0.f;
        #pragma unroll
        for (int l = 0; l < NLEV; ++l) {
            const int base = l * HRHC + hb;
            const float qc = qg[base] * mval;            // masked at source
            const float gl = (qg[base + HC] - qg[base - HC]) * siR;
            const float gn = (qg[base + 1]  - qg[base - 1])  * sjx;
            vals[l] += qc;
            ssqt += qc * qc;
            grad += gl * gl + gn * gn;
        }
        const float du = (Ucol[hb + 1]  - Ucol[hb - 1])  * sjx;
        const float dv = (Vcol[hb + HC] - Vcol[hb - HC]) * siR;
        const float cd = du + dv;
        vals[13] += ssqt;                                // qc masked -> qc^2 masked
        vals[14] = fmaf(mval, grad, vals[14]);
        vals[15] = fmaf(mval, cd * cd, vals[15]);
    }

    // ---- reduction: 4-step 16-lane-group butterfly + LDS transpose (16 values) ----
    #pragma unroll
    for (int k = 0; k < 16; ++k) {
        float x = vals[k];
        x += __shfl_xor(x, 8, 64);
        x += __shfl_xor(x, 4, 64);
        x += __shfl_xor(x, 2, 64);
        x += __shfl_xor(x, 1, 64);
        vals[k] = x;   // every lane in an aligned 16-group now holds all 16 group sums
    }
    const int g = threadIdx.x >> 4, k16 = threadIdx.x & 15;
    float myv = vals[0];
    #pragma unroll
    for (int k = 1; k < 16; ++k) if (k16 == k) myv = vals[k];   // static-index select (no scratch)

    __syncthreads();                         // all Ucol/Vcol reads done -> safe to re-use as red
    float (*red)[16] = (float (*)[16])uvred;
    red[g][k16] = myv;
    __syncthreads();

    if (threadIdx.x < 16) {
        const int k = threadIdx.x;
        float s = 0.f;
        #pragma unroll
        for (int g2 = 0; g2 < 16; ++g2) s += red[g2][k];
        int target;
        if (k < 13)       target = ACC_SUM + b * 13 + k;
        else if (k == 13) target = ACC_SSQ + b;
        else if (k == 14) target = ACC_GRAD;
        else              target = ACC_MASS;
        const int bank = (b * NWG + blockIdx.x) & (NBANK - 1);
        atomicAdd(&ws[WS_ACC + bank * BANKSTRIDE + target], s);
    }
}

// ---------------- finalize: sum banks, apply formulas ----------------
__global__ void pl_finalize_kernel(const float* __restrict__ ws, float* __restrict__ out) {
    __shared__ float tot[N_ACC];
    const int t = threadIdx.x;
    if (t < N_ACC) {
        float s = 0.f;
        for (int bk = 0; bk < NBANK; ++bk) s += ws[WS_ACC + bk * BANKSTRIDE + t];
        tot[t] = s;
    }
    __syncthreads();
    if (t == 0) {
        const float N = (float)SLICE;
        float s2 = 0.f;
        for (int s = 0; s < 2 * NLEV; ++s) s2 += tot[ACC_SUM + s] * tot[ACC_SUM + s];
        const float ssq = tot[ACC_SSQ + 0] + tot[ACC_SSQ + 1];
        // sum over (b,l) of (ssq_bl - sum_bl^2/N)/(N-1), then /26 — ssq collapsed by linearity
        float vmean = (ssq - s2 / N) / (N - 1.0f) * (1.0f / (2.0f * NLEV));
        float gmean = tot[ACC_GRAD] / (float)(NBATCH * NLEV * SLICE);
        float mmean = tot[ACC_MASS] / (float)(NBATCH * SLICE);
        out[0] = vmean + 0.1f * gmean + mmean;          // spectra_loss statically 0
    }
}

extern "C" void kernel_launch(void* const* d_in, const int* in_sizes, int n_in,
                              void* d_out, int out_size, void* d_ws, size_t ws_size,
                              hipStream_t stream) {
    const float* u    = (const float*)d_in[0];
    const float* v    = (const float*)d_in[1];
    const float* plev = (const float*)d_in[2];
    float* ws  = (float*)d_ws;
    float* out = (float*)d_out;

    hipLaunchKernelGGL(pl_setup_kernel, dim3(1), dim3(1024), 0, stream, plev, ws);
    hipLaunchKernelGGL(pl_fused_kernel, dim3(NWG, NBATCH), dim3(256), 0, stream, u, v, ws);
    hipLaunchKernelGGL(pl_finalize_kernel, dim3(1), dim3(64), 0, stream, ws, out);
}

// Round 4
// 90.018 us; speedup vs baseline: 1.4122x; 1.0266x over previous
//
#include <hip/hip_runtime.h>
#include <math.h>
#include <stdint.h>

#define LATN 721
#define LONN 1440
#define NLEV 13
#define NBATCH 2
#define SLICE (LATN * LONN)              // 1,038,240
#define BATSTRIDE (NLEV * SLICE)

// fused-tile geometry (TI=12: halo ratio 476/384=1.24)
#define TI 12
#define TJ 32
#define HR (TI + 2)                      // 14 halo rows
#define HC (TJ + 2)                      // 34 halo cols
#define HRHC (HR * HC)                   // 476
#define NPTS (TI * TJ)                   // 384 interior points
#define NRT 61                           // ceil(721/12)
#define NCT 45                           // 1440/32
#define NWG (NRT * NCT)                  // 2745

// staged tile: rows i0-2..i0+13 (16), cols j0-4..j0+35 (40, 16B-aligned)
#define SROWS 16
#define SCOLS 40
#define SFLTS (SROWS * SCOLS)            // 640 floats per array
#define BUFFLTS (2 * SFLTS)              // u + v = 1280 floats = 5120 B
#define NBUF 4                           // ring depth (k=4, d=2 prefetch)

// ---- ws float layout ----
#define NBANK      128
#define BANKSTRIDE 64
#define WS_ACC     0                     // [NBANK*BANKSTRIDE]
#define ACC_SUM    0        // [26] per (b,l) sums
#define ACC_SSQ    26       // [2]  per-batch total sum-of-squares
#define ACC_GRAD   28
#define ACC_MASS   29
#define N_ACC      30
#define WS_INVDX   (NBANK * BANKSTRIDE)          // [721]
#define WS_FCOR    (WS_INVDX + LATN)             // [721]
#define WS_W       (WS_FCOR + LATN)              // [13]
#define WS_INVDP   (WS_W + NLEV)
#define WS_INV2DP  (WS_INVDP + 1)

constexpr float INV_R     = (float)(1.0 / 6371000.0);
constexpr float INV_DLAT  = (float)(720.0 / M_PI);
constexpr float INV_2DLAT = (float)(360.0 / M_PI);
constexpr float INV_DLON  = (float)(1440.0 / (2.0 * M_PI));
constexpr float INV_2DLON = (float)(720.0 / (2.0 * M_PI));
constexpr float QG_COEF   = 1e-4f;   // F0^2 / N^2

// ---------------- setup: row tables, weights, zero accumulators ----------------
__global__ void pl_setup_kernel(const float* __restrict__ plev, float* __restrict__ ws) {
    const int t = threadIdx.x;
    if (t < LATN) {
        double lat;
        if (t == 0)            lat = (double)(-(float)(M_PI / 2.0));
        else if (t == LATN-1)  lat = (double)( (float)(M_PI / 2.0));
        else                   lat = (double)((float)(-M_PI / 2.0 + (double)t * (M_PI / 720.0)));
        double c = cos(lat);
        if (c < 1e-8) c = 1e-8;                      // matches jnp.clip(cos, 1e-8)
        ws[WS_INVDX + t] = (float)(1.0 / (6371000.0 * c));
        ws[WS_FCOR  + t] = (float)(2.0 * 7.292e-05 * sin(lat));
    }
    if (t < NLEV) {
        float p[NLEV];
        #pragma unroll
        for (int l = 0; l < NLEV; ++l) p[l] = plev[l] * 100.0f;
        float dpl[NLEV-1];
        #pragma unroll
        for (int l = 0; l < NLEV-1; ++l) dpl[l] = p[l+1] - p[l];
        float raw;
        if (t == 0)            raw = dpl[0] * 0.5f;
        else if (t == NLEV-1)  raw = dpl[NLEV-2] * 0.5f;
        else                   raw = (dpl[t-1] + dpl[t]) * 0.5f;
        float s = dpl[0] * 0.5f + dpl[NLEV-2] * 0.5f;
        #pragma unroll
        for (int l = 1; l < NLEV-1; ++l) s += (dpl[l-1] + dpl[l]) * 0.5f;
        if (s < 1e-8f) s = 1e-8f;
        ws[WS_W + t] = raw / s;
    }
    if (t == 0) {
        float sd = 0.f;
        for (int l = 0; l < NLEV-1; ++l) sd += plev[l+1] - plev[l];
        float dp = sd / (float)(NLEV-1) * 100.0f;    // mean(diff)*100 (hPa->Pa)
        ws[WS_INVDP]  = 1.0f / dp;
        ws[WS_INV2DP] = 1.0f / (2.0f * dp);
    }
    for (int z = t; z < NBANK * BANKSTRIDE; z += 1024) ws[WS_ACC + z] = 0.0f;
}

// ---------------- helpers ----------------
__device__ __forceinline__ int swz_nwg(int orig, int nwg) {
    // bijective XCD-chunk swizzle (m204)
    const int q = nwg >> 3, r = nwg & 7;
    const int x = orig & 7, k = orig >> 3;
    return (x < r ? x * (q + 1) : r * (q + 1) + (x - r) * q) + k;
}

__device__ __forceinline__ void gl_lds16(const float* g, float* l) {
    // async 16B global->LDS; LDS dest = wave-uniform base + lane*16 (m97/m104)
    __builtin_amdgcn_global_load_lds((const __attribute__((address_space(1))) void*)g,
                                     (__attribute__((address_space(3))) void*)l,
                                     16, 0, 0);
}

#define VMCNT(n) asm volatile("s_waitcnt vmcnt(" #n ")" ::: "memory")

// ---------------- fused kernel: async-staged u/v tiles, qg in LDS, one pass ----------------
__launch_bounds__(256, 4)
__global__ void pl_fused_kernel(const float* __restrict__ u, const float* __restrict__ v,
                                float* __restrict__ ws)
{
    __shared__ float stg[NBUF * BUFFLTS];    // 4 x 5,120 B = 20,480 B staging ring
    __shared__ float qg[NLEV * HRHC];        // 24,752 B
    __shared__ float uvred[2 * HRHC];        // Ucol/Vcol; reused as red[16][16]
    float* Ucol = uvred;
    float* Vcol = uvred + HRHC;
    // total LDS = 49,040 B -> 3 WG/CU

    const int tid = threadIdx.x;
    const int b  = blockIdx.y;
    const int wg = swz_nwg(blockIdx.x, NWG);
    const int rt = wg / NCT, ct = wg - rt * NCT;
    const int i0 = rt * TI, j0 = ct * TJ;

    const float* ub = u + (size_t)b * BATSTRIDE;
    const float* vb = v + (size_t)b * BATSTRIDE;

    // ---- preamble: all ws-table VMEM up front (keeps vmcnt counting exact) ----
    const float idp = ws[WS_INVDP], i2dp = ws[WS_INV2DP];
    float wlev[NLEV];
    #pragma unroll
    for (int l = 0; l < NLEV; ++l) wlev[l] = ws[WS_W + l];

    // per-point setup: 2 points per thread (hidx = tid, tid+256 clamped)
    float vo[2][NLEV];
    float wu[2] = {0.f, 0.f}, wv[2] = {0.f, 0.f};
    int oU_c[2], oU_p[2], oU_m[2], oV_c[2], oV_p[2], oV_m[2];
    float psc[2], psr[2], pfc[2];
    #pragma unroll
    for (int q = 0; q < 2; ++q) {
        const int hidx = (q == 0) ? tid : min(tid + 256, HRHC - 1);
        const int hr = hidx / HC, hc = hidx - hr * HC;
        const int r = max(0, min(i0 - 1 + hr, LATN - 1));
        const int c = max(0, min(j0 - 1 + hc, LONN - 1));
        const int rp = min(r + 1, LATN - 1), rm = max(r - 1, 0);
        const int cp = min(c + 1, LONN - 1), cm = max(c - 1, 0);
        // LDS-tile coords: t = row - (i0-2), s = col - (j0-4); clamped slots never read
        const int tc = r - i0 + 2, tp = rp - i0 + 2, tm = rm - i0 + 2;
        const int sc_ = c - j0 + 4, sp_ = cp - j0 + 4, sm_ = cm - j0 + 4;
        oU_c[q] = tc * SCOLS + sc_;
        oU_p[q] = tp * SCOLS + sc_;
        oU_m[q] = tm * SCOLS + sc_;
        oV_c[q] = tc * SCOLS + sc_ + SFLTS;
        oV_p[q] = tc * SCOLS + sp_ + SFLTS;
        oV_m[q] = tc * SCOLS + sm_ + SFLTS;
        psc[q] = ((c == 0 || c == LONN - 1) ? INV_DLON : INV_2DLON) * ws[WS_INVDX + r];
        psr[q] = ((r == 0 || r == LATN - 1) ? INV_DLAT : INV_2DLAT) * INV_R;
        pfc[q] = ws[WS_FCOR + r];
    }

    // ---- staging slot decode: 320 float4 slots/level, wave w owns [80w, 80w+80) ----
    const int wid = tid >> 6, lane = tid & 63;
    const int slotA = wid * 80 + lane;                       // 64 lanes
    const int slotB = min(wid * 80 + 64 + lane, 319);        // lanes<16 meaningful
    const float* srcA; const float* srcB;
    {
        const int arrA = slotA / 160, remA = slotA - arrA * 160;
        const int tA = remA / 10, cgA = remA - tA * 10;
        const int RA = max(0, min(i0 - 2 + tA, LATN - 1));
        const int CA = max(0, min(j0 - 4 + cgA * 4, LONN - 4));   // 16B-contiguous, in-bounds
        srcA = (arrA ? vb : ub) + ((size_t)RA * LONN + CA);
        const int arrB = slotB / 160, remB = slotB - arrB * 160;
        const int tB = remB / 10, cgB = remB - tB * 10;
        const int RB = max(0, min(i0 - 2 + tB, LATN - 1));
        const int CB = max(0, min(j0 - 4 + cgB * 4, LONN - 4));
        srcB = (arrB ? vb : ub) + ((size_t)RB * LONN + CB);
    }

    #define STAGE(lev) do {                                                    \
        const int bb_ = ((lev) & 3) * BUFFLTS;                                 \
        gl_lds16(srcA + (size_t)(lev) * SLICE, &stg[bb_ + wid * 320]);         \
        if (lane < 16)                                                         \
            gl_lds16(srcB + (size_t)(lev) * SLICE, &stg[bb_ + wid * 320 + 256]); \
    } while (0)

    // drain preamble VMEM so counted vmcnt below sees only staging ops
    asm volatile("s_waitcnt vmcnt(0)" ::: "memory");
    __builtin_amdgcn_sched_barrier(0);

    // ---- phase 1: counted-vmcnt pipeline, 2 levels of prefetch (T3/T4) ----
    STAGE(0);
    STAGE(1);
    #pragma unroll
    for (int l = 0; l < NLEV; ++l) {
        if (l + 2 < NLEV) STAGE(l + 2);
        // outstanding after issue: 2 instrs/level in flight for (l+1),(l+2)
        if (l < NLEV - 2)       { VMCNT(4); }
        else if (l == NLEV - 2) { VMCNT(2); }
        else                    { VMCNT(0); }
        __builtin_amdgcn_s_barrier();         // all waves' level-l tile staged
        __builtin_amdgcn_sched_barrier(0);    // no ds_read hoists above this point
        const int bb = (l & 3) * BUFFLTS;
        #pragma unroll
        for (int q = 0; q < 2; ++q) {
            vo[q][l] = (stg[bb + oV_p[q]] - stg[bb + oV_m[q]]) * psc[q]
                     - (stg[bb + oU_p[q]] - stg[bb + oU_m[q]]) * psr[q];
            wu[q] = fmaf(wlev[l], stg[bb + oU_c[q]], wu[q]);
            wv[q] = fmaf(wlev[l], stg[bb + oV_c[q]], wv[q]);
        }
    }

    // ---- vertical stencil epilogue (rolling 3-reg window, identical math) ----
    #pragma unroll
    for (int q = 0; q < 2; ++q) {
        const bool valid = (q == 0) || (tid + 256 < HRHC);
        if (valid) {
            const int hidx = (q == 0) ? tid : tid + 256;
            Ucol[hidx] = wu[q];
            Vcol[hidx] = wv[q];
            float vp1m = (vo[q][1] - vo[q][0]) * idp;
            float vp1c = (vo[q][2] - vo[q][0]) * i2dp;
            qg[0 * HRHC + hidx] = vo[q][0] + pfc[q] + QG_COEF * ((vp1c - vp1m) * idp);
            #pragma unroll
            for (int l = 1; l < NLEV - 1; ++l) {
                const float vp1n = (l == NLEV - 2) ? (vo[q][NLEV-1] - vo[q][NLEV-2]) * idp
                                                   : (vo[q][l+2] - vo[q][l]) * i2dp;
                qg[l * HRHC + hidx] = vo[q][l] + pfc[q] + QG_COEF * ((vp1n - vp1m) * i2dp);
                vp1m = vp1c; vp1c = vp1n;
            }
            qg[(NLEV-1) * HRHC + hidx] = vo[q][NLEV-1] + pfc[q] + QG_COEF * ((vp1c - vp1m) * idp);
        }
    }
    __syncthreads();

    // ---- phase 2: pure-LDS stencils over 384 interior points ----
    float vals[16];
    #pragma unroll
    for (int k = 0; k < 16; ++k) vals[k] = 0.f;

    for (int p = tid; p < NPTS; p += 256) {
        const int oi = p >> 5, oj = p & 31;
        const int i = i0 + oi, j = j0 + oj;
        const float mval = (i < LATN) ? 1.f : 0.f;
        const int ic = min(i, LATN - 1);
        const int hb = (oi + 1) * HC + (oj + 1);
        const float siR = ((ic == 0 || ic == LATN - 1) ? INV_DLAT : INV_2DLAT) * INV_R;
        const float sjx = ((j == 0 || j == LONN - 1) ? INV_DLON : INV_2DLON) * ws[WS_INVDX + ic];

        float ssqt = 0.f, grad = 0.f;
        #pragma unroll
        for (int l = 0; l < NLEV; ++l) {
            const int base = l * HRHC + hb;
            const float qc = qg[base] * mval;            // masked at source
            const float gl = (qg[base + HC] - qg[base - HC]) * siR;
            const float gn = (qg[base + 1]  - qg[base - 1])  * sjx;
            vals[l] += qc;
            ssqt += qc * qc;
            grad += gl * gl + gn * gn;
        }
        const float du = (Ucol[hb + 1]  - Ucol[hb - 1])  * sjx;
        const float dv = (Vcol[hb + HC] - Vcol[hb - HC]) * siR;
        const float cd = du + dv;
        vals[13] += ssqt;
        vals[14] = fmaf(mval, grad, vals[14]);
        vals[15] = fmaf(mval, cd * cd, vals[15]);
    }

    // ---- reduction: 4-step 16-lane-group butterfly + LDS transpose ----
    #pragma unroll
    for (int k = 0; k < 16; ++k) {
        float x = vals[k];
        x += __shfl_xor(x, 8, 64);
        x += __shfl_xor(x, 4, 64);
        x += __shfl_xor(x, 2, 64);
        x += __shfl_xor(x, 1, 64);
        vals[k] = x;
    }
    const int g = tid >> 4, k16 = tid & 15;
    float myv = vals[0];
    #pragma unroll
    for (int k = 1; k < 16; ++k) if (k16 == k) myv = vals[k];   // static-index select

    __syncthreads();                         // Ucol/Vcol reads done -> reuse as red
    float (*red)[16] = (float (*)[16])uvred;
    red[g][k16] = myv;
    __syncthreads();

    if (tid < 16) {
        const int k = tid;
        float s = 0.f;
        #pragma unroll
        for (int g2 = 0; g2 < 16; ++g2) s += red[g2][k];
        int target;
        if (k < 13)       target = ACC_SUM + b * 13 + k;
        else if (k == 13) target = ACC_SSQ + b;
        else if (k == 14) target = ACC_GRAD;
        else              target = ACC_MASS;
        const int bank = (b * NWG + blockIdx.x) & (NBANK - 1);
        atomicAdd(&ws[WS_ACC + bank * BANKSTRIDE + target], s);
    }
    #undef STAGE
}

// ---------------- finalize: sum banks, apply formulas ----------------
__global__ void pl_finalize_kernel(const float* __restrict__ ws, float* __restrict__ out) {
    __shared__ float tot[N_ACC];
    const int t = threadIdx.x;
    if (t < N_ACC) {
        float s = 0.f;
        for (int bk = 0; bk < NBANK; ++bk) s += ws[WS_ACC + bk * BANKSTRIDE + t];
        tot[t] = s;
    }
    __syncthreads();
    if (t == 0) {
        const float N = (float)SLICE;
        float s2 = 0.f;
        for (int s = 0; s < 2 * NLEV; ++s) s2 += tot[ACC_SUM + s] * tot[ACC_SUM + s];
        const float ssq = tot[ACC_SSQ + 0] + tot[ACC_SSQ + 1];
        float vmean = (ssq - s2 / N) / (N - 1.0f) * (1.0f / (2.0f * NLEV));
        float gmean = tot[ACC_GRAD] / (float)(NBATCH * NLEV * SLICE);
        float mmean = tot[ACC_MASS] / (float)(NBATCH * SLICE);
        out[0] = vmean + 0.1f * gmean + mmean;          // spectra_loss statically 0
    }
}

extern "C" void kernel_launch(void* const* d_in, const int* in_sizes, int n_in,
                              void* d_out, int out_size, void* d_ws, size_t ws_size,
                              hipStream_t stream) {
    const float* u    = (const float*)d_in[0];
    const float* v    = (const float*)d_in[1];
    const float* plev = (const float*)d_in[2];
    float* ws  = (float*)d_ws;
    float* out = (float*)d_out;

    hipLaunchKernelGGL(pl_setup_kernel, dim3(1), dim3(1024), 0, stream, plev, ws);
    hipLaunchKernelGGL(pl_fused_kernel, dim3(NWG, NBATCH), dim3(256), 0, stream, u, v, ws);
    hipLaunchKernelGGL(pl_finalize_kernel, dim3(1), dim3(64), 0, stream, ws, out);
}